// Round 15
// baseline (115.618 us; speedup 1.0000x reference)
//
#include <hip/hip_runtime.h>
#include <hip/hip_bf16.h>

typedef __attribute__((ext_vector_type(4))) float f32x4;
typedef __attribute__((ext_vector_type(8))) __bf16 bf16x8;

#define NCTX 8192
#define DH 128
#define ROWE 4096                    /* floats between consecutive positions */
#define SC2 0.12751705766482797f     /* (1/sqrt(128)) * log2(e) */
#define KSTR 136                     /* bf16 row stride in staged buffers */
#define PSTR 40                      /* P lds row stride (shorts) */
#define OSTR 132                     /* O-bounce row stride (floats) */
#define BUFS (32*KSTR)               /* shorts per 8.5KB per-wave buffer */
#define NPRIV 1024                   /* private blocks: 4096 positions s<2048 */
#define NSHRD 1536                   /* shared blocks: 4 waves x 2 positions */

__device__ __forceinline__ unsigned f2bf(float x) {
  union { float f; unsigned u; } un; un.f = x;
  return (un.u + 0x7FFFu + ((un.u >> 16) & 1u)) >> 16;   // RNE f32->bf16 bits
}
__device__ __forceinline__ unsigned pk2(float a, float b) {
  float2 t; t.x = a; t.y = b;
  union { __hip_bfloat162 h; unsigned u; } un;
  un.h = __float22bfloat162_rn(t);
  return un.u;
}

// Stage one 4096-float global row -> LDS bf16 [32][KSTR], fully coalesced.
template<bool NT>
__device__ __forceinline__ void stage_row(const float* __restrict__ src,
                                          unsigned short* dst, int lane) {
  const int jb = lane >> 5, d = 4 * (lane & 31);
#pragma unroll
  for (int half = 0; half < 2; ++half) {
    f32x4 x[8];
#pragma unroll
    for (int ch = 0; ch < 8; ++ch) {
      const f32x4* p = reinterpret_cast<const f32x4*>(src + 4*lane + 256*(half*8 + ch));
      x[ch] = NT ? __builtin_nontemporal_load(p) : *p;
    }
#pragma unroll
    for (int ch = 0; ch < 8; ++ch) {
      const int j = jb + 2*(half*8 + ch);       // head row 0..31
      uint2 wv;
      wv.x = pk2(x[ch][0], x[ch][1]);
      wv.y = pk2(x[ch][2], x[ch][3]);
      *reinterpret_cast<uint2*>(&dst[j*KSTR + d]) = wv;
    }
  }
}

// Private blocks: one wave per position s<2048 (R10 path verbatim).
// Shared blocks: one wave per TWO positions s>=2048 — K/V row 8191 coop-staged
// once per block; wave stages Q(sA), issues Q(sA+1) raw loads to registers
// (land under compute A), computes A, converts q1 regs -> LDS (no HBM wait),
// computes B. Doubles in-flight HBM streams per wave chain at peak VGPR ~128.
__global__ __launch_bounds__(256, 3) void hda(
    const float* __restrict__ q, const float* __restrict__ kg,
    const float* __restrict__ v, float* __restrict__ out)
{
  extern __shared__ __align__(16) unsigned short lds[];   // 6 bufs of BUFS shorts

  const int tid  = threadIdx.x;
  const int w    = tid >> 6;
  const int lane = tid & 63;
  const int c = lane & 15;    // frag row/col index
  const int g = lane >> 4;    // lane group 0..3
  const int jb = lane >> 5, dcol = 4 * (lane & 31);   // staging lane map

  unsigned short* sb = lds + w * BUFS;    // per-wave buf

  if (blockIdx.x < NPRIV) {
    // ================= private path (R10 verbatim; r = 4s exact) =================
    const int p = blockIdx.x * 4 + w;     // 0..4095
    const int b = p >> 11;
    const int s = p & 2047;
    const int r = 4 * s;

    const float* qsrc = q  + ((size_t)b * NCTX + s) * ROWE;
    const float* ksrc = kg + ((size_t)b * NCTX + r) * ROWE;
    const float* vsrc = v  + ((size_t)b * NCTX + r) * ROWE;
    float*       op   = out + ((size_t)b * NCTX + s) * ROWE;

    stage_row<true>(qsrc, sb, lane);
    bf16x8 qa[2][4];
#pragma unroll
    for (int t = 0; t < 2; ++t)
#pragma unroll
      for (int ks = 0; ks < 4; ++ks)
        qa[t][ks] = *reinterpret_cast<const bf16x8*>(&sb[(t*16 + c)*KSTR + ks*32 + g*8]);

    stage_row<false>(ksrc, sb, lane);
    bf16x8 kf[2][4];
#pragma unroll
    for (int t = 0; t < 2; ++t)
#pragma unroll
      for (int ks = 0; ks < 4; ++ks)
        kf[t][ks] = *reinterpret_cast<const bf16x8*>(&sb[(t*16 + c)*KSTR + ks*32 + g*8]);

    f32x4 vx[8];
#pragma unroll
    for (int ch = 0; ch < 8; ++ch)
      vx[ch] = *reinterpret_cast<const f32x4*>(vsrc + 4*lane + 256*ch);
    __builtin_amdgcn_sched_barrier(0);

    f32x4 S[2][2];
#pragma unroll
    for (int it = 0; it < 2; ++it)
#pragma unroll
      for (int jt = 0; jt < 2; ++jt) {
        f32x4 acc = (f32x4)0.0f;
#pragma unroll
        for (int ks = 0; ks < 4; ++ks)
          acc = __builtin_amdgcn_mfma_f32_16x16x32_bf16(qa[it][ks], kf[jt][ks], acc, 0, 0, 0);
        S[it][jt] = acc;
      }

#pragma unroll
    for (int ch = 0; ch < 8; ++ch) {
      uint2 wv;
      wv.x = pk2(vx[ch][0], vx[ch][1]);
      wv.y = pk2(vx[ch][2], vx[ch][3]);
      *reinterpret_cast<uint2*>(&sb[(jb + 2*ch)*KSTR + dcol]) = wv;
    }
#pragma unroll
    for (int ch = 0; ch < 8; ++ch)
      vx[ch] = *reinterpret_cast<const f32x4*>(vsrc + 4*lane + 256*(8 + ch));
    __builtin_amdgcn_sched_barrier(0);

    float pp[2][2][4], inv[2][4];
#pragma unroll
    for (int it = 0; it < 2; ++it) {
      float ls[4] = {0.f, 0.f, 0.f, 0.f};
#pragma unroll
      for (int jt = 0; jt < 2; ++jt)
#pragma unroll
        for (int rr = 0; rr < 4; ++rr) {
          float e = exp2f(S[it][jt][rr] * SC2);
          pp[it][jt][rr] = e;
          ls[rr] += e;
        }
#pragma unroll
      for (int m = 1; m <= 8; m <<= 1)
#pragma unroll
        for (int rr = 0; rr < 4; ++rr)
          ls[rr] += __shfl_xor(ls[rr], m);
#pragma unroll
      for (int rr = 0; rr < 4; ++rr) inv[it][rr] = 1.0f / ls[rr];
    }

#pragma unroll
    for (int ch = 0; ch < 8; ++ch) {
      uint2 wv;
      wv.x = pk2(vx[ch][0], vx[ch][1]);
      wv.y = pk2(vx[ch][2], vx[ch][3]);
      *reinterpret_cast<uint2*>(&sb[(jb + 2*(8 + ch))*KSTR + dcol]) = wv;
    }

    bf16x8 va[8];
#pragma unroll
    for (int dt = 0; dt < 8; ++dt) {
      unsigned t0 = sb[(g*8 + 0)*KSTR + dt*16 + c];
      unsigned t1 = sb[(g*8 + 1)*KSTR + dt*16 + c];
      unsigned t2 = sb[(g*8 + 2)*KSTR + dt*16 + c];
      unsigned t3 = sb[(g*8 + 3)*KSTR + dt*16 + c];
      unsigned t4 = sb[(g*8 + 4)*KSTR + dt*16 + c];
      unsigned t5 = sb[(g*8 + 5)*KSTR + dt*16 + c];
      unsigned t6 = sb[(g*8 + 6)*KSTR + dt*16 + c];
      unsigned t7 = sb[(g*8 + 7)*KSTR + dt*16 + c];
      union { unsigned u[4]; bf16x8 f; } un;
      un.u[0] = t0 | (t1 << 16); un.u[1] = t2 | (t3 << 16);
      un.u[2] = t4 | (t5 << 16); un.u[3] = t6 | (t7 << 16);
      va[dt] = un.f;
    }

#pragma unroll
    for (int it = 0; it < 2; ++it)
#pragma unroll
      for (int jt = 0; jt < 2; ++jt)
#pragma unroll
        for (int rr = 0; rr < 4; ++rr)
          sb[(it*16 + g*4 + rr)*PSTR + jt*16 + c] =
              (unsigned short)f2bf(pp[it][jt][rr] * inv[it][rr]);

    bf16x8 pa[2];
    pa[0] = *reinterpret_cast<const bf16x8*>(&sb[c*PSTR + g*8]);
    pa[1] = *reinterpret_cast<const bf16x8*>(&sb[(16 + c)*PSTR + g*8]);

    float* ob = reinterpret_cast<float*>(sb);
#pragma unroll
    for (int it = 0; it < 2; ++it) {
      f32x4 o[8];
#pragma unroll
      for (int dt = 0; dt < 8; ++dt)
        o[dt] = __builtin_amdgcn_mfma_f32_16x16x32_bf16(va[dt], pa[it], (f32x4)0.0f, 0, 0, 0);
#pragma unroll
      for (int dt = 0; dt < 8; ++dt)
        *reinterpret_cast<f32x4*>(&ob[c*OSTR + dt*16 + g*4]) = o[dt];
#pragma unroll
      for (int ch = 0; ch < 8; ++ch) {
        const int flat = 4*lane + 256*ch;
        const int row = flat >> 7, col = flat & 127;
        f32x4 y = *reinterpret_cast<const f32x4*>(&ob[row*OSTR + col]);
        __builtin_nontemporal_store(y, reinterpret_cast<f32x4*>(op + it*2048 + flat));
      }
    }
    return;
  }

  // ================= shared path: 2 positions per wave, K/V row 8191 =================
  const int bi = blockIdx.x - NPRIV;            // 0..1535
  const int b  = (bi >= 768) ? 1 : 0;
  const int sA = 2048 + (bi - b*768)*8 + w*2;   // positions sA, sA+1

  const float* qb_ = q   + (size_t)b * NCTX * ROWE;
  float*       ob_ = out + (size_t)b * NCTX * ROWE;
  const unsigned short* kbuf = lds + 4*BUFS;
  const unsigned short* vbuf = lds + 5*BUFS;

  // coop one-time staging of K/V row 8191 (L2-hot)
  {
    const float* kr8 = kg + ((size_t)b * NCTX + (NCTX-1)) * ROWE;
    const float* vr8 = v  + ((size_t)b * NCTX + (NCTX-1)) * ROWE;
    const int d0 = 4 * (tid & 31), jj = tid >> 5;
#pragma unroll
    for (int ch = 0; ch < 4; ++ch) {
      const int fo = 4*tid + 1024*ch;
      const int j  = jj + 8*ch;
      f32x4 xk = *reinterpret_cast<const f32x4*>(kr8 + fo);
      f32x4 xv = *reinterpret_cast<const f32x4*>(vr8 + fo);
      uint2 wk, wv2;
      wk.x  = pk2(xk[0], xk[1]); wk.y  = pk2(xk[2], xk[3]);
      wv2.x = pk2(xv[0], xv[1]); wv2.y = pk2(xv[2], xv[3]);
      *reinterpret_cast<uint2*>(&lds[4*BUFS + j*KSTR + d0]) = wk;
      *reinterpret_cast<uint2*>(&lds[5*BUFS + j*KSTR + d0]) = wv2;
    }
    __syncthreads();
  }

  // stage Q(sA) -> LDS; then issue Q(sA+1) raw loads (land under compute A)
  stage_row<true>(qb_ + (size_t)sA * ROWE, sb, lane);
  f32x4 q1[16];
#pragma unroll
  for (int ch = 0; ch < 16; ++ch)
    q1[ch] = __builtin_nontemporal_load(reinterpret_cast<const f32x4*>(
        qb_ + (size_t)(sA + 1) * ROWE + 4*lane + 256*ch));
  __builtin_amdgcn_sched_barrier(0);

#pragma unroll 1
  for (int i = 0; i < 2; ++i) {
    const int s = sA + i;

    if (i == 1) {
      // convert prefetched q1 regs -> sb (no HBM wait; DS in-order vs O-flush)
#pragma unroll
      for (int ch = 0; ch < 16; ++ch) {
        uint2 wv;
        wv.x = pk2(q1[ch][0], q1[ch][1]);
        wv.y = pk2(q1[ch][2], q1[ch][3]);
        *reinterpret_cast<uint2*>(&sb[(jb + 2*ch)*KSTR + dcol]) = wv;
      }
    }

    bf16x8 qa[2][4];
#pragma unroll
    for (int t = 0; t < 2; ++t)
#pragma unroll
      for (int ks = 0; ks < 4; ++ks)
        qa[t][ks] = *reinterpret_cast<const bf16x8*>(&sb[(t*16 + c)*KSTR + ks*32 + g*8]);

    bf16x8 kf[2][4];   // re-read per position (keeps peak VGPR under cap)
#pragma unroll
    for (int t = 0; t < 2; ++t)
#pragma unroll
      for (int ks = 0; ks < 4; ++ks)
        kf[t][ks] = *reinterpret_cast<const bf16x8*>(&kbuf[(t*16 + c)*KSTR + ks*32 + g*8]);

    f32x4 S[2][2];
#pragma unroll
    for (int it = 0; it < 2; ++it)
#pragma unroll
      for (int jt = 0; jt < 2; ++jt) {
        f32x4 acc = (f32x4)0.0f;
#pragma unroll
        for (int ks = 0; ks < 4; ++ks)
          acc = __builtin_amdgcn_mfma_f32_16x16x32_bf16(qa[it][ks], kf[jt][ks], acc, 0, 0, 0);
        S[it][jt] = acc;
      }

    float pp[2][2][4], inv[2][4];
#pragma unroll
    for (int it = 0; it < 2; ++it) {
      float ls[4] = {0.f, 0.f, 0.f, 0.f};
#pragma unroll
      for (int jt = 0; jt < 2; ++jt)
#pragma unroll
        for (int rr = 0; rr < 4; ++rr) {
          float e = exp2f(S[it][jt][rr] * SC2);
          pp[it][jt][rr] = e;
          ls[rr] += e;
        }
#pragma unroll
      for (int m = 1; m <= 8; m <<= 1)
#pragma unroll
        for (int rr = 0; rr < 4; ++rr)
          ls[rr] += __shfl_xor(ls[rr], m);
#pragma unroll
      for (int rr = 0; rr < 4; ++rr) inv[it][rr] = 1.0f / ls[rr];
    }

    bf16x8 va[8];
#pragma unroll
    for (int dt = 0; dt < 8; ++dt) {
      unsigned t0 = vbuf[(g*8 + 0)*KSTR + dt*16 + c];
      unsigned t1 = vbuf[(g*8 + 1)*KSTR + dt*16 + c];
      unsigned t2 = vbuf[(g*8 + 2)*KSTR + dt*16 + c];
      unsigned t3 = vbuf[(g*8 + 3)*KSTR + dt*16 + c];
      unsigned t4 = vbuf[(g*8 + 4)*KSTR + dt*16 + c];
      unsigned t5 = vbuf[(g*8 + 5)*KSTR + dt*16 + c];
      unsigned t6 = vbuf[(g*8 + 6)*KSTR + dt*16 + c];
      unsigned t7 = vbuf[(g*8 + 7)*KSTR + dt*16 + c];
      union { unsigned u[4]; bf16x8 f; } un;
      un.u[0] = t0 | (t1 << 16); un.u[1] = t2 | (t3 << 16);
      un.u[2] = t4 | (t5 << 16); un.u[3] = t6 | (t7 << 16);
      va[dt] = un.f;
    }

#pragma unroll
    for (int it = 0; it < 2; ++it)
#pragma unroll
      for (int jt = 0; jt < 2; ++jt)
#pragma unroll
        for (int rr = 0; rr < 4; ++rr)
          sb[(it*16 + g*4 + rr)*PSTR + jt*16 + c] =
              (unsigned short)f2bf(pp[it][jt][rr] * inv[it][rr]);

    bf16x8 pa[2];
    pa[0] = *reinterpret_cast<const bf16x8*>(&sb[c*PSTR + g*8]);
    pa[1] = *reinterpret_cast<const bf16x8*>(&sb[(16 + c)*PSTR + g*8]);

    float* op = ob_ + (size_t)s * ROWE;
    float* ob = reinterpret_cast<float*>(sb);
#pragma unroll
    for (int it = 0; it < 2; ++it) {
      f32x4 o[8];
#pragma unroll
      for (int dt = 0; dt < 8; ++dt)
        o[dt] = __builtin_amdgcn_mfma_f32_16x16x32_bf16(va[dt], pa[it], (f32x4)0.0f, 0, 0, 0);
#pragma unroll
      for (int dt = 0; dt < 8; ++dt)
        *reinterpret_cast<f32x4*>(&ob[c*OSTR + dt*16 + g*4]) = o[dt];
#pragma unroll
      for (int ch = 0; ch < 8; ++ch) {
        const int flat = 4*lane + 256*ch;
        const int row = flat >> 7, col = flat & 127;
        f32x4 y = *reinterpret_cast<const f32x4*>(&ob[row*OSTR + col]);
        __builtin_nontemporal_store(y, reinterpret_cast<f32x4*>(op + it*2048 + flat));
      }
    }
  }
}

extern "C" void kernel_launch(void* const* d_in, const int* in_sizes, int n_in,
                              void* d_out, int out_size, void* d_ws, size_t ws_size,
                              hipStream_t stream) {
  const float* q = (const float*)d_in[0];
  const float* k = (const float*)d_in[1];
  const float* v = (const float*)d_in[2];
  float* o = (float*)d_out;
  // 1024 private blocks (1 pos/wave) + 1536 shared blocks (2 pos/wave); 52224 B LDS
  hda<<<dim3(NPRIV + NSHRD, 1, 1), dim3(256, 1, 1), 6 * BUFS * 2, stream>>>(q, k, v, o);
}